// Round 1
// baseline (215.383 us; speedup 1.0000x reference)
//
#include <hip/hip_runtime.h>
#include <hip/hip_bf16.h>

typedef unsigned short u16;
typedef __bf16 bf16x8 __attribute__((ext_vector_type(8)));
typedef float f32x4 __attribute__((ext_vector_type(4)));

#define DEVI __device__ __forceinline__

// ---- problem constants ----
constexpr int Bn = 8, Nn = 1032, Cn = 768, Hn = 12, HDn = 64;
constexpr int NPADc = 1088;            // N padded to tile multiple for safe tile loads
constexpr int MTOT = Bn * Nn;          // 8256
constexpr int MPAD = 8320;             // 65 * 128
constexpr int KVN = 1536;              // k+v output channels
constexpr int PFXc = 8;
constexpr float SCALEc = 0.125f;       // hd^-0.5
constexpr float LOG2Ec = 1.4426950408889634f;
constexpr float INV2S2c = 0.02f;       // 1/(2*5^2)

// ---- workspace layout (bytes). total ~55.8 MB ----
constexpr size_t OFF_XB  = 0;
constexpr size_t SZ_XB   = (size_t)MPAD * Cn * 2;       // x bf16, padded rows zeroed
constexpr size_t OFF_WKV = OFF_XB + SZ_XB;
constexpr size_t SZ_WKV  = (size_t)KVN * Cn * 2;        // w_qkv rows 768..2304 bf16
constexpr size_t OFF_WP  = OFF_WKV + SZ_WKV;
constexpr size_t SZ_WP   = (size_t)Cn * Cn * 2;         // w_proj bf16
constexpr size_t OFF_K   = OFF_WP + SZ_WP;
constexpr size_t SZ_K    = (size_t)Bn * Hn * NPADc * HDn * 2;  // k [B,H,NPAD,64]
constexpr size_t OFF_V   = OFF_K + SZ_K;
constexpr size_t SZ_V    = SZ_K;                        // v^T [B,H,64,NPAD]
constexpr size_t OFF_AT  = OFF_V + SZ_V;                // attn out bf16 [MPAD][768]

DEVI u16 f2bf(float f) {
  __hip_bfloat16 h = __float2bfloat16(f);
  return *reinterpret_cast<u16*>(&h);
}

// async global->LDS, 16B per lane; LDS dest = wave-uniform base + lane*16 (HW)
DEVI void glds16(const void* g, void* l) {
  __builtin_amdgcn_global_load_lds((const __attribute__((address_space(1))) void*)g,
                                   (__attribute__((address_space(3))) void*)l, 16, 0, 0);
}

// ---------------- prep: fp32 -> bf16 conversions ----------------
__global__ __launch_bounds__(256) void prep_kernel(
    const float* __restrict__ x, const float* __restrict__ wqkv,
    const float* __restrict__ wproj, u16* __restrict__ xb,
    u16* __restrict__ wkvb, u16* __restrict__ wpb) {
  const int n1 = MPAD * Cn / 4, n2 = KVN * Cn / 4, n3 = Cn * Cn / 4;
  const int tot = n1 + n2 + n3;
  for (int i = blockIdx.x * blockDim.x + threadIdx.x; i < tot; i += gridDim.x * blockDim.x) {
    const float* src; u16* dst;
    if (i < n1) {
      int e = i * 4;
      src = (e < MTOT * Cn) ? (x + e) : nullptr;   // pad rows -> zero
      dst = xb + e;
    } else if (i < n1 + n2) {
      int e = (i - n1) * 4;
      src = wqkv + Cn * Cn + e;                    // skip q-weights (q unused!)
      dst = wkvb + e;
    } else {
      int e = (i - n1 - n2) * 4;
      src = wproj + e;
      dst = wpb + e;
    }
    float4 f = src ? *(const float4*)src : make_float4(0.f, 0.f, 0.f, 0.f);
    *(ushort4*)dst = make_ushort4(f2bf(f.x), f2bf(f.y), f2bf(f.z), f2bf(f.w));
  }
}

// ---------------- shared 128x128 BK=64 bt-GEMM mainloop ----------------
// A [.,768] row-major bf16, Bm [.,768] row-major bf16 (rows = output cols).
// LDS tiles [128][64] bf16, 128B rows, chunk-XOR swizzle via pre-swizzled
// global source (global_load_lds writes linearly; m173 trick).
DEVI void gemm_mainloop(const u16* __restrict__ A, const u16* __restrict__ Bm,
                        int m0, int n0, char* sA, char* sB, f32x4 (&acc)[4][4]) {
  const int tid = threadIdx.x, lane = tid & 63, w = tid >> 6;
  const int ln = lane & 15, lg = lane >> 4;
  const int wm = (w >> 1) * 64, wn = (w & 1) * 64;
  for (int kt = 0; kt < 12; ++kt) {
#pragma unroll
    for (int i = 0; i < 4; ++i) {
      const int c = i * 256 + tid, r = c >> 3, cb = c & 7, gcb = cb ^ (r & 7);
      const char* ga = (const char*)(A + (size_t)(m0 + r) * Cn + kt * 64) + gcb * 16;
      glds16(ga, sA + i * 4096 + w * 1024);
      const char* gb = (const char*)(Bm + (size_t)(n0 + r) * Cn + kt * 64) + gcb * 16;
      glds16(gb, sB + i * 4096 + w * 1024);
    }
    __syncthreads();
#pragma unroll
    for (int ks = 0; ks < 2; ++ks) {
      bf16x8 af[4], bfr[4];
#pragma unroll
      for (int s = 0; s < 4; ++s) {
        const int ra = wm + s * 16 + ln;
        af[s] = *(const bf16x8*)(sA + ra * 128 + (((ks * 4 + lg) ^ (ra & 7)) << 4));
        const int rb = wn + s * 16 + ln;
        bfr[s] = *(const bf16x8*)(sB + rb * 128 + (((ks * 4 + lg) ^ (rb & 7)) << 4));
      }
#pragma unroll
      for (int s = 0; s < 4; ++s)
#pragma unroll
        for (int t = 0; t < 4; ++t)
          acc[s][t] = __builtin_amdgcn_mfma_f32_16x16x32_bf16(af[s], bfr[t], acc[s][t], 0, 0, 0);
    }
    __syncthreads();
  }
}

// ---------------- kernel A: kv = x @ w_kv^T + b, split k / v^T ----------------
__global__ __launch_bounds__(256) void kv_gemm(
    const u16* __restrict__ xb, const u16* __restrict__ wkvb,
    const float* __restrict__ bqkv, u16* __restrict__ khead, u16* __restrict__ vT) {
  __shared__ __align__(16) char sA[16384];
  __shared__ __align__(16) char sB[16384];
  const int m0 = blockIdx.y * 128, n0 = blockIdx.x * 128;
  f32x4 acc[4][4] = {};
  gemm_mainloop(xb, wkvb, m0, n0, sA, sB, acc);
  const int tid = threadIdx.x, lane = tid & 63, w = tid >> 6;
  const int ln = lane & 15, lg = lane >> 4;
  const int wm = (w >> 1) * 64, wn = (w & 1) * 64;
  const bool isV = (n0 >= Cn);   // block-uniform (768 = 6*128)
#pragma unroll
  for (int t = 0; t < 4; ++t) {
    const int n = n0 + wn + t * 16 + ln;          // [0,1536)
    const float bias = bqkv[Cn + n];
    const int nn = isV ? (n - Cn) : n;
    const int h = nn >> 6, d = nn & 63;
#pragma unroll
    for (int s = 0; s < 4; ++s) {
#pragma unroll
      for (int r = 0; r < 4; ++r) {
        const int m = m0 + wm + s * 16 + lg * 4 + r;
        if (m < MTOT) {
          const int b = m / Nn, nr = m - b * Nn;
          const u16 val = f2bf(acc[s][t][r] + bias);
          if (!isV) khead[((size_t)(b * Hn + h) * NPADc + nr) * HDn + d] = val;
          else      vT[((size_t)(b * Hn + h) * HDn + d) * NPADc + nr] = val;
        }
      }
    }
  }
}

// ---------------- kernel B: fused gauss attention ----------------
// grid (17 q-tiles, 96 bh). 4 waves x 16 q-rows. No online max needed
// (scores <= ~6 -> exp <= ~500, fp32-safe).
__global__ __launch_bounds__(256) void attn_kernel(
    const u16* __restrict__ khead, const u16* __restrict__ vT, u16* __restrict__ attn) {
  __shared__ __align__(16) char sK[8192];
  __shared__ __align__(16) char sV[8192];
  __shared__ __align__(16) char sP[64 * 144];     // padded stride kills bank conflicts
  __shared__ float tA[1024], tAL[1024];
  const int tid = threadIdx.x, lane = tid & 63, w = tid >> 6;
  const int ln = lane & 15, lg = lane >> 4;
  const int qt = blockIdx.x, bh = blockIdx.y;
  const int qbase = qt * 64;

  // Gauss table: tA[a*32+b] = exp(-(a-b)^2/50); tAL = tA*log2e (fold one factor)
  for (int i = tid; i < 1024; i += 256) {
    float diff = (float)((i >> 5) - (i & 31));
    float e = exp2f(-diff * diff * (INV2S2c * LOG2Ec));
    tA[i] = e;
    tAL[i] = e * LOG2Ec;
  }

  // Q fragments in registers (rows may be pad rows -> finite garbage, not stored)
  const char* qp = (const char*)(khead + ((size_t)bh * NPADc + qbase + w * 16 + ln) * HDn);
  const bf16x8 qf0 = *(const bf16x8*)(qp + lg * 16);
  const bf16x8 qf1 = *(const bf16x8*)(qp + 64 + lg * 16);

  // per-output-row constants
  int qrow[4], oAL[4], oA[4];
  bool qok[4];
  float denv[4] = {0.f, 0.f, 0.f, 0.f};
#pragma unroll
  for (int r = 0; r < 4; ++r) {
    int q = qbase + w * 16 + lg * 4 + r;
    qrow[r] = q;
    int qc = (q < Nn) ? q : (Nn - 1);             // clamp pad rows for table index
    int pq = qc - PFXc;
    qok[r] = (pq >= 0);
    int iq = (pq < 0) ? 0 : (pq >> 5), jq = (pq < 0) ? 0 : (pq & 31);
    oAL[r] = iq * 32;
    oA[r] = jq * 32;
  }
  f32x4 oacc[4] = {};
  __syncthreads();

  for (int mc = 0; mc < 17; ++mc) {
    const int mbase = mc * 64;
    // stage K tile [64][64] and V^T tile [64 d][64 m], XOR-source-swizzled
#pragma unroll
    for (int i = 0; i < 2; ++i) {
      const int c = i * 256 + tid, r = c >> 3, cb = c & 7, gcb = cb ^ (r & 7);
      const char* gk = (const char*)(khead + ((size_t)bh * NPADc + mbase + r) * HDn) + gcb * 16;
      glds16(gk, sK + i * 4096 + w * 1024);
      const char* gv = (const char*)(vT + ((size_t)bh * HDn + r) * NPADc + mbase) + gcb * 16;
      glds16(gv, sV + i * 4096 + w * 1024);
    }
    __syncthreads();

    // S = Q K^T  (rows=q, cols=m)
    f32x4 sacc[4] = {};
#pragma unroll
    for (int ms = 0; ms < 4; ++ms) {
      const int r = ms * 16 + ln;
      bf16x8 kf0 = *(const bf16x8*)(sK + r * 128 + ((lg ^ (r & 7)) << 4));
      bf16x8 kf1 = *(const bf16x8*)(sK + r * 128 + (((4 + lg) ^ (r & 7)) << 4));
      sacc[ms] = __builtin_amdgcn_mfma_f32_16x16x32_bf16(qf0, kf0, sacc[ms], 0, 0, 0);
      sacc[ms] = __builtin_amdgcn_mfma_f32_16x16x32_bf16(qf1, kf1, sacc[ms], 0, 0, 0);
    }

    // P = exp(S*scale + Ai*Aj), masked; write wave-local LDS tile
#pragma unroll
    for (int ms = 0; ms < 4; ++ms) {
      const int mg = mbase + ms * 16 + ln;
      const bool mok = (mg < Nn);
      const int pm = mg - PFXc;
      const bool gok = mok && (pm >= 0);
      const int im = gok ? (pm >> 5) : 0, jm = gok ? (pm & 31) : 0;
#pragma unroll
      for (int r = 0; r < 4; ++r) {
        float addl = (gok && qok[r]) ? tAL[oAL[r] + im] * tA[oA[r] + jm] : 0.f;
        float p = mok ? exp2f(fmaf(sacc[ms][r], SCALEc * LOG2Ec, addl)) : 0.f;
        denv[r] += p;
        *(u16*)(sP + (w * 16 + lg * 4 + r) * 144 + (ms * 16 + ln) * 2) = f2bf(p);
      }
    }

    // O += P V   (A = P rows q, B = v^T rows d; wave-local P, no barrier needed)
#pragma unroll
    for (int km = 0; km < 2; ++km) {
      bf16x8 pf = *(const bf16x8*)(sP + (w * 16 + ln) * 144 + km * 64 + lg * 16);
#pragma unroll
      for (int ds = 0; ds < 4; ++ds) {
        const int r = ds * 16 + ln;
        bf16x8 vf = *(const bf16x8*)(sV + r * 128 + (((km * 4 + lg) ^ (r & 7)) << 4));
        oacc[ds] = __builtin_amdgcn_mfma_f32_16x16x32_bf16(pf, vf, oacc[ds], 0, 0, 0);
      }
    }
    __syncthreads();   // protect K/V before next stage
  }

  // denominator: reduce over 16 col-lanes
#pragma unroll
  for (int r = 0; r < 4; ++r) {
    float d = denv[r];
    d += __shfl_xor(d, 1); d += __shfl_xor(d, 2);
    d += __shfl_xor(d, 4); d += __shfl_xor(d, 8);
    denv[r] = d;
  }
  const int b = bh / Hn, h = bh - b * Hn;
#pragma unroll
  for (int ds = 0; ds < 4; ++ds) {
#pragma unroll
    for (int r = 0; r < 4; ++r) {
      const int q = qrow[r];
      if (q < Nn)
        attn[((size_t)(b * Nn + q)) * Cn + h * HDn + ds * 16 + ln] =
            f2bf(oacc[ds][r] / denv[r]);
    }
  }
}

// ---------------- kernel C: out = attn @ w_proj^T + b_proj (fp32) ----------------
__global__ __launch_bounds__(256) void proj_gemm(
    const u16* __restrict__ at, const u16* __restrict__ wpb,
    const float* __restrict__ bproj, float* __restrict__ out) {
  __shared__ __align__(16) char sA[16384];
  __shared__ __align__(16) char sB[16384];
  const int m0 = blockIdx.y * 128, n0 = blockIdx.x * 128;
  f32x4 acc[4][4] = {};
  gemm_mainloop(at, wpb, m0, n0, sA, sB, acc);
  const int tid = threadIdx.x, lane = tid & 63, w = tid >> 6;
  const int ln = lane & 15, lg = lane >> 4;
  const int wm = (w >> 1) * 64, wn = (w & 1) * 64;
#pragma unroll
  for (int t = 0; t < 4; ++t) {
    const int n = n0 + wn + t * 16 + ln;
    const float bias = bproj[n];
#pragma unroll
    for (int s = 0; s < 4; ++s) {
#pragma unroll
      for (int r = 0; r < 4; ++r) {
        const int m = m0 + wm + s * 16 + lg * 4 + r;
        if (m < MTOT) out[(size_t)m * Cn + n] = acc[s][t][r] + bias;
      }
    }
  }
}

extern "C" void kernel_launch(void* const* d_in, const int* in_sizes, int n_in,
                              void* d_out, int out_size, void* d_ws, size_t ws_size,
                              hipStream_t stream) {
  const float* x     = (const float*)d_in[0];
  const float* wqkv  = (const float*)d_in[1];
  const float* bqkv  = (const float*)d_in[2];
  const float* wproj = (const float*)d_in[3];
  const float* bproj = (const float*)d_in[4];
  char* ws = (char*)d_ws;
  u16* xb    = (u16*)(ws + OFF_XB);
  u16* wkvb  = (u16*)(ws + OFF_WKV);
  u16* wpb   = (u16*)(ws + OFF_WP);
  u16* khead = (u16*)(ws + OFF_K);
  u16* vT    = (u16*)(ws + OFF_V);
  u16* attn  = (u16*)(ws + OFF_AT);

  prep_kernel<<<2048, 256, 0, stream>>>(x, wqkv, wproj, xb, wkvb, wpb);
  kv_gemm<<<dim3(12, 65), 256, 0, stream>>>(xb, wkvb, bqkv, khead, vT);
  attn_kernel<<<dim3(17, 96), 256, 0, stream>>>(khead, vT, attn);
  proj_gemm<<<dim3(6, 65), 256, 0, stream>>>(attn, wpb, bproj, (float*)d_out);
}

// Round 2
// 182.680 us; speedup vs baseline: 1.1790x; 1.1790x over previous
//
#include <hip/hip_runtime.h>
#include <hip/hip_bf16.h>

typedef unsigned short u16;
typedef __bf16 bf16x8 __attribute__((ext_vector_type(8)));
typedef float f32x4 __attribute__((ext_vector_type(4)));

#define DEVI __device__ __forceinline__

// ---- problem constants ----
constexpr int Bn = 8, Nn = 1032, Cn = 768, Hn = 12, HDn = 64;
constexpr int NPADc = 1088;
constexpr int MTOT = Bn * Nn;          // 8256
constexpr int MPAD = 8320;             // 65 * 128
constexpr int KVN = 1536;
constexpr int PFXc = 8;
constexpr int NPADQ = NPADc - Nn;      // 56 zero-padded m positions
constexpr float SCALEc = 0.125f;
constexpr float LOG2Ec = 1.4426950408889634f;
constexpr float C1c = SCALEc * LOG2Ec;
constexpr float INV2S2c = 0.02f;

// ---- workspace layout ----
constexpr size_t OFF_XB  = 0;
constexpr size_t SZ_XB   = (size_t)MPAD * Cn * 2;
constexpr size_t OFF_WKV = OFF_XB + SZ_XB;
constexpr size_t SZ_WKV  = (size_t)KVN * Cn * 2;
constexpr size_t OFF_WP  = OFF_WKV + SZ_WKV;
constexpr size_t SZ_WP   = (size_t)Cn * Cn * 2;
constexpr size_t OFF_K   = OFF_WP + SZ_WP;
constexpr size_t SZ_K    = (size_t)Bn * Hn * NPADc * HDn * 2;
constexpr size_t OFF_V   = OFF_K + SZ_K;
constexpr size_t SZ_V    = SZ_K;
constexpr size_t OFF_AT  = OFF_V + SZ_V;

DEVI u16 f2bf(float f) {
  __hip_bfloat16 h = __float2bfloat16(f);
  return *reinterpret_cast<u16*>(&h);
}

DEVI void glds16(const void* g, void* l) {
  __builtin_amdgcn_global_load_lds((const __attribute__((address_space(1))) void*)g,
                                   (__attribute__((address_space(3))) void*)l, 16, 0, 0);
}

// ---------------- prep: fp32 -> bf16 conversions + zero pad regions ----------------
__global__ __launch_bounds__(256) void prep_kernel(
    const float* __restrict__ x, const float* __restrict__ wqkv,
    const float* __restrict__ wproj, u16* __restrict__ xb,
    u16* __restrict__ wkvb, u16* __restrict__ wpb,
    u16* __restrict__ khead, u16* __restrict__ vT) {
  const int n1 = MPAD * Cn / 4, n2 = KVN * Cn / 4, n3 = Cn * Cn / 4;
  const int z1 = 96 * 448;   // khead pad rows: 96 bh * 56*64*2B / 16B
  const int z2 = 6144 * 7;   // vT pad cols: 96*64 stripes * 112B / 16B
  const int nc = n1 + n2 + n3;
  const int tot = nc + z1 + z2;
  for (int i = blockIdx.x * blockDim.x + threadIdx.x; i < tot; i += gridDim.x * blockDim.x) {
    if (i < nc) {
      const float* src; u16* dst;
      if (i < n1) {
        int e = i * 4;
        src = (e < MTOT * Cn) ? (x + e) : nullptr;
        dst = xb + e;
      } else if (i < n1 + n2) {
        int e = (i - n1) * 4;
        src = wqkv + Cn * Cn + e;               // skip q-weights (q unused)
        dst = wkvb + e;
      } else {
        int e = (i - n1 - n2) * 4;
        src = wproj + e;
        dst = wpb + e;
      }
      float4 f = src ? *(const float4*)src : make_float4(0.f, 0.f, 0.f, 0.f);
      *(ushort4*)dst = make_ushort4(f2bf(f.x), f2bf(f.y), f2bf(f.z), f2bf(f.w));
    } else if (i < nc + z1) {
      int j = i - nc, bh = j / 448, c = j - bh * 448;
      char* dst = (char*)khead + ((size_t)bh * NPADc + Nn) * HDn * 2 + c * 16;
      *(ushort4*)dst = make_ushort4(0, 0, 0, 0);
      *(ushort4*)(dst + 8) = make_ushort4(0, 0, 0, 0);
    } else {
      int j = i - nc - z1, st = j / 7, c = j - st * 7;
      char* dst = (char*)vT + ((size_t)st * NPADc + Nn) * 2 + c * 16;
      *(ushort4*)dst = make_ushort4(0, 0, 0, 0);
      *(ushort4*)(dst + 8) = make_ushort4(0, 0, 0, 0);
    }
  }
}

// ---------------- shared 128x128 BK=64 bt-GEMM mainloop ----------------
DEVI void gemm_mainloop(const u16* __restrict__ A, const u16* __restrict__ Bm,
                        int m0, int n0, char* sA, char* sB, f32x4 (&acc)[4][4]) {
  const int tid = threadIdx.x, lane = tid & 63, w = tid >> 6;
  const int ln = lane & 15, lg = lane >> 4;
  const int wm = (w >> 1) * 64, wn = (w & 1) * 64;
  for (int kt = 0; kt < 12; ++kt) {
#pragma unroll
    for (int i = 0; i < 4; ++i) {
      const int c = i * 256 + tid, r = c >> 3, cb = c & 7, gcb = cb ^ (r & 7);
      const char* ga = (const char*)(A + (size_t)(m0 + r) * Cn + kt * 64) + gcb * 16;
      glds16(ga, sA + i * 4096 + w * 1024);
      const char* gb = (const char*)(Bm + (size_t)(n0 + r) * Cn + kt * 64) + gcb * 16;
      glds16(gb, sB + i * 4096 + w * 1024);
    }
    __syncthreads();
#pragma unroll
    for (int ks = 0; ks < 2; ++ks) {
      bf16x8 af[4], bfr[4];
#pragma unroll
      for (int s = 0; s < 4; ++s) {
        const int ra = wm + s * 16 + ln;
        af[s] = *(const bf16x8*)(sA + ra * 128 + (((ks * 4 + lg) ^ (ra & 7)) << 4));
        const int rb = wn + s * 16 + ln;
        bfr[s] = *(const bf16x8*)(sB + rb * 128 + (((ks * 4 + lg) ^ (rb & 7)) << 4));
      }
#pragma unroll
      for (int s = 0; s < 4; ++s)
#pragma unroll
        for (int t = 0; t < 4; ++t)
          acc[s][t] = __builtin_amdgcn_mfma_f32_16x16x32_bf16(af[s], bfr[t], acc[s][t], 0, 0, 0);
    }
    __syncthreads();
  }
}

// ---------------- kernel A: kv = x @ w_kv^T + b, split k / v^T ----------------
__global__ __launch_bounds__(256) void kv_gemm(
    const u16* __restrict__ xb, const u16* __restrict__ wkvb,
    const float* __restrict__ bqkv, u16* __restrict__ khead, u16* __restrict__ vT) {
  __shared__ __align__(16) char sA[16384];
  __shared__ __align__(16) char sB[16384];
  const int m0 = blockIdx.y * 128, n0 = blockIdx.x * 128;
  f32x4 acc[4][4] = {};
  gemm_mainloop(xb, wkvb, m0, n0, sA, sB, acc);
  const int tid = threadIdx.x, lane = tid & 63, w = tid >> 6;
  const int ln = lane & 15, lg = lane >> 4;
  const int wm = (w >> 1) * 64, wn = (w & 1) * 64;
  const bool isV = (n0 >= Cn);
#pragma unroll
  for (int t = 0; t < 4; ++t) {
    const int n = n0 + wn + t * 16 + ln;
    const float bias = bqkv[Cn + n];
    const int nn = isV ? (n - Cn) : n;
    const int h = nn >> 6, d = nn & 63;
#pragma unroll
    for (int s = 0; s < 4; ++s) {
#pragma unroll
      for (int r = 0; r < 4; ++r) {
        const int m = m0 + wm + s * 16 + lg * 4 + r;
        if (m < MTOT) {
          const int b = m / Nn, nr = m - b * Nn;
          const u16 val = f2bf(acc[s][t][r] + bias);
          if (!isV) khead[((size_t)(b * Hn + h) * NPADc + nr) * HDn + d] = val;
          else      vT[((size_t)(b * Hn + h) * HDn + d) * NPADc + nr] = val;
        }
      }
    }
  }
}

// ---------------- kernel B: fused gauss attention ----------------
// 1632 blocks (XCD-chunked: 1632 = 8*204, 204 = 12bh*17qt -> per-XCD K/V locality).
// Zero-padded K/V rows -> p_pad = 1.0 exactly, den -= 56; no per-element masks.
__global__ __launch_bounds__(256) void attn_kernel(
    const u16* __restrict__ khead, const u16* __restrict__ vT, u16* __restrict__ attn) {
  __shared__ __align__(16) char sK[2][8192];
  __shared__ __align__(16) char sV[2][8192];
  __shared__ __align__(16) char sP[64 * 144];
  __shared__ float tAL[1089], tA[1089];   // 33-stride: col/row 32 = 0 (mask-free gauss)
  const int tid = threadIdx.x, lane = tid & 63, w = tid >> 6;
  const int ln = lane & 15, lg = lane >> 4;
  const int xcd = blockIdx.x & 7, loc = blockIdx.x >> 3;
  const int lid = xcd * 204 + loc;
  const int qt = lid % 17, bh = lid / 17;
  const int qbase = qt * 64;

  for (int i = tid; i < 1089; i += 256) {
    int a = i / 33, b = i - a * 33;
    float d = (float)(a - b);
    float e = (a < 32 && b < 32) ? exp2f(-d * d * (INV2S2c * LOG2Ec)) : 0.f;
    tAL[i] = e * LOG2Ec;
    tA[i] = e;
  }

  const char* qp = (const char*)(khead + ((size_t)bh * NPADc + qbase + w * 16 + ln) * HDn);
  const bf16x8 qf0 = *(const bf16x8*)(qp + lg * 16);
  const bf16x8 qf1 = *(const bf16x8*)(qp + 64 + lg * 16);

  int qrow[4], oAL[4], oA[4];
  float denv[4] = {0.f, 0.f, 0.f, 0.f};
#pragma unroll
  for (int r = 0; r < 4; ++r) {
    int q = qbase + w * 16 + lg * 4 + r;
    qrow[r] = q;
    int pq = q - PFXc;
    bool qv = (pq >= 0) && (q < Nn);
    oAL[r] = qv ? (pq >> 5) * 33 : 32 * 33;   // invalid q -> zero row
    oA[r]  = qv ? (pq & 31) * 33 : 0;
  }
  f32x4 oacc[4] = {};

  // prologue stage into buf 0
#pragma unroll
  for (int i = 0; i < 2; ++i) {
    const int c = i * 256 + tid, r = c >> 3, cb = c & 7, gcb = cb ^ (r & 7);
    glds16((const char*)(khead + ((size_t)bh * NPADc + r) * HDn) + gcb * 16,
           sK[0] + i * 4096 + w * 1024);
    glds16((const char*)(vT + ((size_t)bh * HDn + r) * NPADc) + gcb * 16,
           sV[0] + i * 4096 + w * 1024);
  }
  __syncthreads();

  for (int mc = 0; mc < 17; ++mc) {
    const int cur = mc & 1;
    const int mbase = mc * 64;
    if (mc < 16) {
      const int nb = mbase + 64;
#pragma unroll
      for (int i = 0; i < 2; ++i) {
        const int c = i * 256 + tid, r = c >> 3, cb = c & 7, gcb = cb ^ (r & 7);
        glds16((const char*)(khead + ((size_t)bh * NPADc + nb + r) * HDn) + gcb * 16,
               sK[cur ^ 1] + i * 4096 + w * 1024);
        glds16((const char*)(vT + ((size_t)bh * HDn + r) * NPADc + nb) + gcb * 16,
               sV[cur ^ 1] + i * 4096 + w * 1024);
      }
    }

    // S = Q K^T
    f32x4 sacc[4] = {};
#pragma unroll
    for (int ms = 0; ms < 4; ++ms) {
      const int r = ms * 16 + ln;
      bf16x8 kf0 = *(const bf16x8*)(sK[cur] + r * 128 + ((lg ^ (r & 7)) << 4));
      bf16x8 kf1 = *(const bf16x8*)(sK[cur] + r * 128 + (((4 + lg) ^ (r & 7)) << 4));
      sacc[ms] = __builtin_amdgcn_mfma_f32_16x16x32_bf16(qf0, kf0, sacc[ms], 0, 0, 0);
      sacc[ms] = __builtin_amdgcn_mfma_f32_16x16x32_bf16(qf1, kf1, sacc[ms], 0, 0, 0);
    }

    // P = exp2(S*c1 + AiL*Aj), mask-free via zero table row/col
#pragma unroll
    for (int ms = 0; ms < 4; ++ms) {
      const int pm = mbase + ms * 16 + ln - PFXc;
      const int imi = ((unsigned)pm >= 1024u) ? 32 : (pm >> 5);   // pad/prefix -> zero col
      const int jm = pm & 31;
#pragma unroll
      for (int r = 0; r < 4; ++r) {
        float addl = tAL[oAL[r] + imi] * tA[oA[r] + jm];
        float p = exp2f(fmaf(sacc[ms][r], C1c, addl));
        denv[r] += p;
        *(u16*)(sP + (w * 16 + lg * 4 + r) * 144 + (ms * 16 + ln) * 2) = f2bf(p);
      }
    }

    // O += P V (wave-local sP, no barrier needed before reads)
#pragma unroll
    for (int km = 0; km < 2; ++km) {
      bf16x8 pf = *(const bf16x8*)(sP + (w * 16 + ln) * 144 + km * 64 + lg * 16);
#pragma unroll
      for (int ds = 0; ds < 4; ++ds) {
        const int r = ds * 16 + ln;
        bf16x8 vf = *(const bf16x8*)(sV[cur] + r * 128 + (((km * 4 + lg) ^ (r & 7)) << 4));
        oacc[ds] = __builtin_amdgcn_mfma_f32_16x16x32_bf16(pf, vf, oacc[ds], 0, 0, 0);
      }
    }
    __syncthreads();   // next-buf staged + everyone done with cur
  }

#pragma unroll
  for (int r = 0; r < 4; ++r) {
    float d = denv[r];
    d += __shfl_xor(d, 1); d += __shfl_xor(d, 2);
    d += __shfl_xor(d, 4); d += __shfl_xor(d, 8);
    denv[r] = 1.0f / (d - (float)NPADQ);   // remove the 56 exact-1.0 pad terms
  }
  const int b = bh / Hn, h = bh - b * Hn;
#pragma unroll
  for (int ds = 0; ds < 4; ++ds) {
#pragma unroll
    for (int r = 0; r < 4; ++r) {
      const int q = qrow[r];
      if (q < Nn)
        attn[((size_t)(b * Nn + q)) * Cn + h * HDn + ds * 16 + ln] =
            f2bf(oacc[ds][r] * denv[r]);
    }
  }
}

// ---------------- kernel C: out = attn @ w_proj^T + b_proj ----------------
__global__ __launch_bounds__(256) void proj_gemm(
    const u16* __restrict__ at, const u16* __restrict__ wpb,
    const float* __restrict__ bproj, float* __restrict__ out) {
  __shared__ __align__(16) char sA[16384];
  __shared__ __align__(16) char sB[16384];
  const int m0 = blockIdx.y * 128, n0 = blockIdx.x * 128;
  f32x4 acc[4][4] = {};
  gemm_mainloop(at, wpb, m0, n0, sA, sB, acc);
  const int tid = threadIdx.x, lane = tid & 63, w = tid >> 6;
  const int ln = lane & 15, lg = lane >> 4;
  const int wm = (w >> 1) * 64, wn = (w & 1) * 64;
#pragma unroll
  for (int t = 0; t < 4; ++t) {
    const int n = n0 + wn + t * 16 + ln;
    const float bias = bproj[n];
#pragma unroll
    for (int s = 0; s < 4; ++s) {
#pragma unroll
      for (int r = 0; r < 4; ++r) {
        const int m = m0 + wm + s * 16 + lg * 4 + r;
        if (m < MTOT) out[(size_t)m * Cn + n] = acc[s][t][r] + bias;
      }
    }
  }
}

extern "C" void kernel_launch(void* const* d_in, const int* in_sizes, int n_in,
                              void* d_out, int out_size, void* d_ws, size_t ws_size,
                              hipStream_t stream) {
  const float* x     = (const float*)d_in[0];
  const float* wqkv  = (const float*)d_in[1];
  const float* bqkv  = (const float*)d_in[2];
  const float* wproj = (const float*)d_in[3];
  const float* bproj = (const float*)d_in[4];
  char* ws = (char*)d_ws;
  u16* xb    = (u16*)(ws + OFF_XB);
  u16* wkvb  = (u16*)(ws + OFF_WKV);
  u16* wpb   = (u16*)(ws + OFF_WP);
  u16* khead = (u16*)(ws + OFF_K);
  u16* vT    = (u16*)(ws + OFF_V);
  u16* attn  = (u16*)(ws + OFF_AT);

  prep_kernel<<<2048, 256, 0, stream>>>(x, wqkv, wproj, xb, wkvb, wpb, khead, vT);
  kv_gemm<<<dim3(12, 65), 256, 0, stream>>>(xb, wkvb, bqkv, khead, vT);
  attn_kernel<<<1632, 256, 0, stream>>>(khead, vT, attn);
  proj_gemm<<<dim3(6, 65), 256, 0, stream>>>(attn, wpb, bproj, (float*)d_out);
}